// Round 1
// baseline (482.983 us; speedup 1.0000x reference)
//
#include <hip/hip_runtime.h>
#include <math.h>

constexpr int NCOLS = 32768;
constexpr int BLOCK = 256;
constexpr int TOPN  = 8;   // supports k <= 7; setup uses k=3 (threshold = 4th largest)

// Merge two descending-sorted 8-lists; result (top-8 of the union, desc) in a.
// Bitonic: concat a with reverse(b) is bitonic(16); max at dist 8 selects the
// top half (bitonic), then a full 8-element bitonic merge sorts it descending.
__device__ inline void merge8(float* a, const float* b) {
    float s[TOPN];
#pragma unroll
    for (int i = 0; i < TOPN; i++) s[i] = fmaxf(a[i], b[TOPN - 1 - i]);
#pragma unroll
    for (int i = 0; i < 4; i++) {
        float hi = fmaxf(s[i], s[i + 4]);
        float lo = fminf(s[i], s[i + 4]);
        s[i] = hi; s[i + 4] = lo;
    }
#pragma unroll
    for (int g = 0; g < 8; g += 4)
#pragma unroll
        for (int i = 0; i < 2; i++) {
            float hi = fmaxf(s[g + i], s[g + i + 2]);
            float lo = fminf(s[g + i], s[g + i + 2]);
            s[g + i] = hi; s[g + i + 2] = lo;
        }
#pragma unroll
    for (int g = 0; g < 8; g += 2) {
        float hi = fmaxf(s[g], s[g + 1]);
        float lo = fminf(s[g], s[g + 1]);
        s[g] = hi; s[g + 1] = lo;
    }
#pragma unroll
    for (int i = 0; i < TOPN; i++) a[i] = s[i];
}

// Maintain v[0..7] sorted descending; insert x if it beats v[7].
__device__ inline void insert8(float* v, float x) {
    if (x > v[7]) {
        v[7] = x;
#pragma unroll
        for (int i = 7; i > 0; i--) {
            float hi = fmaxf(v[i - 1], v[i]);
            float lo = fminf(v[i - 1], v[i]);
            v[i - 1] = hi; v[i] = lo;
        }
    }
}

__global__ __launch_bounds__(BLOCK) void topk_scale_kernel(
    const float* __restrict__ x, const int* __restrict__ kptr,
    float* __restrict__ out) {
    // +1 pad: stride 9 floats breaks the (tid*8)%32 16-way bank conflict
    __shared__ float lds[BLOCK][TOPN + 1];

    const int row = blockIdx.x;
    const int tid = threadIdx.x;
    const float4* __restrict__ xrow =
        reinterpret_cast<const float4*>(x + (size_t)row * NCOLS);
    float4* __restrict__ orow =
        reinterpret_cast<float4*>(out + (size_t)row * NCOLS);
    const int nvec = NCOLS / 4;  // 8192 float4 per row

    float v[TOPN];
#pragma unroll
    for (int i = 0; i < TOPN; i++) v[i] = -INFINITY;

    // Pass 1: per-thread top-8 over strided float4 loads (coalesced)
    for (int i = tid; i < nvec; i += BLOCK) {
        float4 p = xrow[i];
        insert8(v, p.x);
        insert8(v, p.y);
        insert8(v, p.z);
        insert8(v, p.w);
    }

#pragma unroll
    for (int i = 0; i < TOPN; i++) lds[tid][i] = v[i];
    __syncthreads();

    // LDS tree reduction of sorted-8 lists
    for (int stride = BLOCK / 2; stride > 0; stride >>= 1) {
        if (tid < stride) {
            float a[TOPN], b[TOPN];
#pragma unroll
            for (int i = 0; i < TOPN; i++) {
                a[i] = lds[tid][i];
                b[i] = lds[tid + stride][i];
            }
            merge8(a, b);
#pragma unroll
            for (int i = 0; i < TOPN; i++) lds[tid][i] = a[i];
        }
        __syncthreads();
    }

    int k = *kptr;              // uniform scalar load; k=3 in the harness setup
    if (k > TOPN - 1) k = TOPN - 1;
    const float thr = lds[0][k];  // (k+1)-th largest value of the row

    // Pass 2: apply. Row was just read by this CU -> mostly L2/L3 hits.
    for (int i = tid; i < nvec; i += BLOCK) {
        float4 p = xrow[i];
        float4 o;
        o.x = (p.x >= thr) ? p.x * 10.0f : p.x;
        o.y = (p.y >= thr) ? p.y * 10.0f : p.y;
        o.z = (p.z >= thr) ? p.z * 10.0f : p.z;
        o.w = (p.w >= thr) ? p.w * 10.0f : p.w;
        orow[i] = o;
    }
}

extern "C" void kernel_launch(void* const* d_in, const int* in_sizes, int n_in,
                              void* d_out, int out_size, void* d_ws, size_t ws_size,
                              hipStream_t stream) {
    const float* x = (const float*)d_in[0];
    const int* k = (const int*)d_in[1];
    float* out = (float*)d_out;
    const int nrows = in_sizes[0] / NCOLS;  // 2048
    topk_scale_kernel<<<nrows, BLOCK, 0, stream>>>(x, k, out);
}